// Round 6
// baseline (684.635 us; speedup 1.0000x reference)
//
#include <hip/hip_runtime.h>

// GNN layer: m = relu(nf[src] + ef); neigh = segment_sum(m, dst);
// rst = nf + neigh; y = rst @ W^T + b; leaky(0.01); batchnorm(axis=0, biased var).
//
// Edge phase = counting sort by dst (CSR) then wave-per-node register gather.
// Round-5 change: gather processes 2 edges per iteration (lane halves, float4
// loads) to halve the serial latency chain; 3-kernel scan fused to 1.
//
// d_out doubles as the rst/y buffer.
// d_ws layout (bytes):
//   0       stats: 512 f32
//   2048    bsum:  (unused, kept for layout stability)
//   4096    cnt:   40960 int (histogram, padded)
//   167936  offs:  40961 int (CSR offsets)
//   335872  curs:  40000 int (scatter cursors)
//   499712  pairs: 640000 int2 (src, edge_id) sorted by dst
constexpr int NN = 40000;
constexpr int NE = 640000;
constexpr int DD = 128;
constexpr int TN = 128;
constexpr int SCAN_N = 40960;                // padded histogram slots
constexpr int SCAN_T = 1024;
constexpr int SCAN_PER = SCAN_N / SCAN_T;    // 40
constexpr size_t WS_STATS = 0;
constexpr size_t WS_CNT   = 4096;
constexpr size_t WS_OFFS  = 167936;
constexpr size_t WS_CURS  = 335872;
constexpr size_t WS_PAIRS = 499712;
constexpr size_t WS_NEEDED = WS_PAIRS + (size_t)NE * 8;   // 5,619,712 B

// ---------------------------------------------------------------- E0: zero
__global__ __launch_bounds__(256) void k_zero(int* __restrict__ cnt,
                                              float* __restrict__ stats) {
    int i = blockIdx.x * 256 + threadIdx.x;
    if (i < SCAN_N) cnt[i] = 0;
    else if (i < SCAN_N + 512) stats[i - SCAN_N] = 0.0f;
}

// ---------------------------------------------------------------- E1: hist
__global__ __launch_bounds__(256) void k_hist(const int* __restrict__ edst,
                                              int* __restrict__ cnt) {
    int e = blockIdx.x * 256 + threadIdx.x;
    if (e < NE) atomicAdd(&cnt[edst[e]], 1);
}

// ---------------------------------------------------------------- E2: scan (one block)
__global__ __launch_bounds__(1024) void k_scan(const int* __restrict__ cnt,
                                               int* __restrict__ offs,
                                               int* __restrict__ curs) {
    __shared__ int sm[SCAN_T];
    int t = threadIdx.x;
    int base = t * SCAN_PER;
    int run = 0;
#pragma unroll
    for (int i = 0; i < SCAN_PER; ++i) run += cnt[base + i];
    sm[t] = run;
    __syncthreads();
    for (int off = 1; off < SCAN_T; off <<= 1) {      // Hillis-Steele inclusive
        int add = (t >= off) ? sm[t - off] : 0;
        __syncthreads();
        sm[t] += add;
        __syncthreads();
    }
    int excl = sm[t] - run;                            // exclusive prefix of chunk
#pragma unroll
    for (int i = 0; i < SCAN_PER; ++i) {
        int v = cnt[base + i];
        offs[base + i] = excl;
        if (base + i < NN) curs[base + i] = excl;
        excl += v;
    }
    if (t == SCAN_T - 1) offs[SCAN_N] = excl;          // total = NE
}

// ---------------------------------------------------------------- E3: scatter ids
__global__ __launch_bounds__(256) void k_scatter(const int* __restrict__ esrc,
                                                 const int* __restrict__ edst,
                                                 int* __restrict__ curs,
                                                 int2* __restrict__ pairs) {
    int e = blockIdx.x * 256 + threadIdx.x;
    if (e < NE) {
        int d = edst[e];
        int pos = atomicAdd(&curs[d], 1);
        pairs[pos] = make_int2(esrc[e], e);
    }
}

// ---------------------------------------------------------------- E4: gather
// One wave per node. Lane halves process 2 edges per iteration; each lane owns
// a float4 (cols 4*(lane&31)..+3). Cross-half shfl_xor reduce at the end.
__global__ __launch_bounds__(256) void k_gather(const float* __restrict__ nf,
                                                const float* __restrict__ ef,
                                                const int* __restrict__ offs,
                                                const int2* __restrict__ pairs,
                                                float* __restrict__ y) {
    int gt = blockIdx.x * 256 + threadIdx.x;
    int n = gt >> 6;                       // node = global wave id (grid exact)
    int lane = threadIdx.x & 63;
    int h  = lane >> 5;                    // which edge of the pair
    int il = lane & 31;                    // float4 slot within the row
    const float4* ef4 = (const float4*)ef;
    const float4* nf4 = (const float4*)nf;
    int start = offs[n];
    int end   = offs[n + 1];
    float4 acc = make_float4(0.f, 0.f, 0.f, 0.f);
    for (int base = start; base < end; base += 64) {
        int idx = base + lane;
        int2 pr = (idx < end) ? pairs[idx] : make_int2(0, 0);
        int cnt = min(64, end - base);
        int nit = (cnt + 1) >> 1;
        for (int i = 0; i < nit; ++i) {    // 2 edges per iteration
            int j = 2 * i + h;
            int s = __shfl(pr.x, j);
            int e = __shfl(pr.y, j);
            if (j < cnt) {
                float4 a = ef4[(size_t)e * 32 + il];
                float4 b = nf4[(size_t)s * 32 + il];
                acc.x += fmaxf(a.x + b.x, 0.0f);
                acc.y += fmaxf(a.y + b.y, 0.0f);
                acc.z += fmaxf(a.z + b.z, 0.0f);
                acc.w += fmaxf(a.w + b.w, 0.0f);
            }
        }
    }
    float4 r;
    r.x = acc.x + __shfl_xor(acc.x, 32);
    r.y = acc.y + __shfl_xor(acc.y, 32);
    r.z = acc.z + __shfl_xor(acc.z, 32);
    r.w = acc.w + __shfl_xor(acc.w, 32);
    if (h == 0) {
        float4 b = nf4[(size_t)n * 32 + il];           // residual
        r.x += b.x; r.y += b.y; r.z += b.z; r.w += b.w;
        reinterpret_cast<float4*>(y)[(size_t)n * 32 + il] = r;
    }
}

// ---------------------------------------------------------------- fallback path
__global__ __launch_bounds__(256) void k_init(const float* __restrict__ nf,
                                              float* __restrict__ acc,
                                              float* __restrict__ stats) {
    int i = blockIdx.x * 256 + threadIdx.x;
    reinterpret_cast<float4*>(acc)[i] = reinterpret_cast<const float4*>(nf)[i];
    if (blockIdx.x == 0) stats[threadIdx.x] = 0.0f;
}

__global__ __launch_bounds__(256) void k_edge(const float* __restrict__ nf,
                                              const float* __restrict__ ef,
                                              const int* __restrict__ esrc,
                                              const int* __restrict__ edst,
                                              float* __restrict__ acc) {
    const unsigned total = (unsigned)NE * 32u;
    const unsigned stride = gridDim.x * 256u;
    for (unsigned gid = blockIdx.x * 256u + threadIdx.x; gid < total; gid += stride) {
        unsigned e = gid >> 5;
        unsigned c = gid & 31u;
        int s = esrc[e];
        int d = edst[e];
        float4 hs = reinterpret_cast<const float4*>(nf + (size_t)s * DD)[c];
        float4 he = reinterpret_cast<const float4*>(ef + (size_t)e * DD)[c];
        float4 m;
        m.x = fmaxf(hs.x + he.x, 0.0f);
        m.y = fmaxf(hs.y + he.y, 0.0f);
        m.z = fmaxf(hs.z + he.z, 0.0f);
        m.w = fmaxf(hs.w + he.w, 0.0f);
        float* p = acc + (size_t)d * DD + c * 4u;
        unsafeAtomicAdd(p + 0, m.x);
        unsafeAtomicAdd(p + 1, m.y);
        unsafeAtomicAdd(p + 2, m.z);
        unsafeAtomicAdd(p + 3, m.w);
    }
}

// ---------------------------------------------------------------- K3: GEMM
__global__ __launch_bounds__(256, 1) void k_mlp(float* __restrict__ y,
                                                const float* __restrict__ Wm,
                                                const float* __restrict__ bias,
                                                float* __restrict__ stats) {
    __shared__ float Ws[DD][DD];        // (j,k) at col k ^ (((j>>4)&7)<<2)
    __shared__ float As[TN][DD];        // (n,k) at col k ^ (((n>>2)&7)<<2)
    __shared__ float ssum[DD];
    __shared__ float ssumsq[DD];

    const int tid = threadIdx.x;
    const int n0 = blockIdx.x * TN;

    for (int i = tid; i < DD * (DD / 4); i += 256) {
        int j  = i >> 5;
        int k4 = i & 31;
        float4 w = reinterpret_cast<const float4*>(Wm + j * DD)[k4];
        int ks = (k4 * 4) ^ (((j >> 4) & 7) << 2);
        *reinterpret_cast<float4*>(&Ws[j][ks]) = w;
    }
    for (int i = tid; i < TN * (DD / 4); i += 256) {
        int nl = i >> 5;
        int k4 = i & 31;
        int n  = n0 + nl;
        float4 a = make_float4(0.f, 0.f, 0.f, 0.f);
        if (n < NN) a = reinterpret_cast<const float4*>(y + (size_t)n * DD)[k4];
        int ks = (k4 * 4) ^ (((nl >> 2) & 7) << 2);
        *reinterpret_cast<float4*>(&As[nl][ks]) = a;
    }
    if (tid < DD) { ssum[tid] = 0.0f; ssumsq[tid] = 0.0f; }
    __syncthreads();

    const int ng = tid >> 3;
    const int jg = tid & 7;
    const int aswz = (ng & 7) << 2;
    const int wswz = jg << 2;
    const int nb = 4 * ng;

    float acc4[4][16];
#pragma unroll
    for (int i = 0; i < 4; ++i)
#pragma unroll
        for (int jj = 0; jj < 16; ++jj) acc4[i][jj] = 0.0f;

#pragma unroll 2
    for (int t = 0; t < DD / 4; ++t) {
        const int ka = (4 * t) ^ aswz;
        const int kw = (4 * t) ^ wswz;
        float4 a0 = *reinterpret_cast<const float4*>(&As[nb + 0][ka]);
        float4 a1 = *reinterpret_cast<const float4*>(&As[nb + 1][ka]);
        float4 a2 = *reinterpret_cast<const float4*>(&As[nb + 2][ka]);
        float4 a3 = *reinterpret_cast<const float4*>(&As[nb + 3][ka]);
#pragma unroll
        for (int jj = 0; jj < 16; ++jj) {
            float4 w = *reinterpret_cast<const float4*>(&Ws[16 * jg + jj][kw]);
            acc4[0][jj] = fmaf(a0.x, w.x, fmaf(a0.y, w.y, fmaf(a0.z, w.z, fmaf(a0.w, w.w, acc4[0][jj]))));
            acc4[1][jj] = fmaf(a1.x, w.x, fmaf(a1.y, w.y, fmaf(a1.z, w.z, fmaf(a1.w, w.w, acc4[1][jj]))));
            acc4[2][jj] = fmaf(a2.x, w.x, fmaf(a2.y, w.y, fmaf(a2.z, w.z, fmaf(a2.w, w.w, acc4[2][jj]))));
            acc4[3][jj] = fmaf(a3.x, w.x, fmaf(a3.y, w.y, fmaf(a3.z, w.z, fmaf(a3.w, w.w, acc4[3][jj]))));
        }
    }

    float psum[16], psq[16];
#pragma unroll
    for (int jj = 0; jj < 16; ++jj) { psum[jj] = 0.0f; psq[jj] = 0.0f; }

#pragma unroll
    for (int i = 0; i < 4; ++i) {
        int n = n0 + nb + i;
        if (n < NN) {
            float out[16];
#pragma unroll
            for (int jj = 0; jj < 16; ++jj) {
                float v = acc4[i][jj] + bias[16 * jg + jj];
                v = (v >= 0.0f) ? v : 0.01f * v;
                out[jj] = v;
                psum[jj] += v;
                psq[jj]  += v * v;
            }
            float4* dst = reinterpret_cast<float4*>(y + (size_t)n * DD + 16 * jg);
            dst[0] = make_float4(out[0],  out[1],  out[2],  out[3]);
            dst[1] = make_float4(out[4],  out[5],  out[6],  out[7]);
            dst[2] = make_float4(out[8],  out[9],  out[10], out[11]);
            dst[3] = make_float4(out[12], out[13], out[14], out[15]);
        }
    }
#pragma unroll
    for (int jj = 0; jj < 16; ++jj) {
        atomicAdd(&ssum[16 * jg + jj], psum[jj]);
        atomicAdd(&ssumsq[16 * jg + jj], psq[jj]);
    }
    __syncthreads();
    if (tid < DD) {
        unsafeAtomicAdd(&stats[tid],      ssum[tid]);
        unsafeAtomicAdd(&stats[DD + tid], ssumsq[tid]);
    }
}

// ---------------------------------------------------------------- K4: stats
__global__ void k_stats(float* __restrict__ stats,
                        const float* __restrict__ gamma,
                        const float* __restrict__ beta) {
    int j = threadIdx.x;
    if (j < DD) {
        float inv_n = 1.0f / (float)NN;
        float mean = stats[j] * inv_n;
        float var  = stats[DD + j] * inv_n - mean * mean;
        float s = gamma[j] * rsqrtf(var + 1e-5f);
        stats[2 * DD + j] = s;
        stats[3 * DD + j] = beta[j] - mean * s;
    }
}

// ---------------------------------------------------------------- K5: BN
__global__ __launch_bounds__(256) void k_bn(float* __restrict__ y,
                                            const float* __restrict__ stats) {
    int i = blockIdx.x * 256 + threadIdx.x;
    int k4 = i & 31;
    float4 sc = reinterpret_cast<const float4*>(stats + 2 * DD)[k4];
    float4 sh = reinterpret_cast<const float4*>(stats + 3 * DD)[k4];
    float4 v = reinterpret_cast<float4*>(y)[i];
    v.x = fmaf(v.x, sc.x, sh.x);
    v.y = fmaf(v.y, sc.y, sh.y);
    v.z = fmaf(v.z, sc.z, sh.z);
    v.w = fmaf(v.w, sc.w, sh.w);
    reinterpret_cast<float4*>(y)[i] = v;
}

extern "C" void kernel_launch(void* const* d_in, const int* in_sizes, int n_in,
                              void* d_out, int out_size, void* d_ws, size_t ws_size,
                              hipStream_t stream) {
    const float* nf    = (const float*)d_in[0];
    const float* ef    = (const float*)d_in[1];
    const int*   esrc  = (const int*)d_in[2];
    const int*   edst  = (const int*)d_in[3];
    const float* Wm    = (const float*)d_in[4];
    const float* bias  = (const float*)d_in[5];
    const float* gamma = (const float*)d_in[6];
    const float* beta  = (const float*)d_in[7];
    float* y = (float*)d_out;
    char* ws = (char*)d_ws;

    float* stats = (float*)(ws + WS_STATS);
    int*   cnt   = (int*)(ws + WS_CNT);
    int*   offs  = (int*)(ws + WS_OFFS);
    int*   curs  = (int*)(ws + WS_CURS);
    int2*  pairs = (int2*)(ws + WS_PAIRS);

    const int vec_blocks = (NN * DD / 4) / 256;             // 5000, exact
    const int edge_blocks = (NE + 255) / 256;               // 2500

    if (ws_size >= WS_NEEDED) {
        k_zero<<<(SCAN_N + 512 + 255) / 256, 256, 0, stream>>>(cnt, stats);
        k_hist<<<edge_blocks, 256, 0, stream>>>(edst, cnt);
        k_scan<<<1, SCAN_T, 0, stream>>>(cnt, offs, curs);
        k_scatter<<<edge_blocks, 256, 0, stream>>>(esrc, edst, curs, pairs);
        k_gather<<<NN * 64 / 256, 256, 0, stream>>>(nf, ef, offs, pairs, y);
    } else {
        // fallback: atomic scatter path (proven correct, slower)
        k_init<<<vec_blocks, 256, 0, stream>>>(nf, y, stats);
        k_edge<<<2048, 256, 0, stream>>>(nf, ef, esrc, edst, y);
    }
    k_mlp<<<(NN + TN - 1) / TN, 256, 0, stream>>>(y, Wm, bias, stats);
    k_stats<<<1, 128, 0, stream>>>(stats, gamma, beta);
    k_bn<<<vec_blocks, 256, 0, stream>>>(y, stats);
}

// Round 8
// 638.873 us; speedup vs baseline: 1.0716x; 1.0716x over previous
//
#include <hip/hip_runtime.h>

// GNN layer: m = relu(nf[src] + ef); neigh = segment_sum(m, dst);
// rst = nf + neigh; y = rst @ W^T + b; leaky(0.01); batchnorm(axis=0, biased var).
//
// Edge phase = counting sort by dst (CSR) then wave-per-node register gather.
// Round-7: gather inner loop 4-unrolled with CLAMPED indices + masked adds
// (unconditional loads -> compiler batches 8 loads per group, 4x fewer
// serialization points). Scan reverted to proven 3-kernel version (round-5).
//
// d_out doubles as the rst/y buffer.
// d_ws layout (bytes):
//   0       stats: 512 f32
//   2048    bsum:  40 int (scan block sums)
//   4096    cnt:   40960 int (histogram, padded to 40*1024)
//   167936  offs:  40961 int (CSR offsets)
//   335872  curs:  40000 int (scatter cursors)
//   499712  pairs: 640000 int2 (src, edge_id) sorted by dst
constexpr int NN = 40000;
constexpr int NE = 640000;
constexpr int DD = 128;
constexpr int TN = 128;
constexpr int SCAN_B = 40;                   // 40 blocks * 1024 = 40960 slots
constexpr size_t WS_STATS = 0;
constexpr size_t WS_BSUM  = 2048;
constexpr size_t WS_CNT   = 4096;
constexpr size_t WS_OFFS  = 167936;
constexpr size_t WS_CURS  = 335872;
constexpr size_t WS_PAIRS = 499712;
constexpr size_t WS_NEEDED = WS_PAIRS + (size_t)NE * 8;   // 5,619,712 B

// ---------------------------------------------------------------- E0: zero
__global__ __launch_bounds__(256) void k_zero(int* __restrict__ cnt,
                                              float* __restrict__ stats) {
    int i = blockIdx.x * 256 + threadIdx.x;
    if (i < SCAN_B * 1024) cnt[i] = 0;
    else if (i < SCAN_B * 1024 + 512) stats[i - SCAN_B * 1024] = 0.0f;
}

// ---------------------------------------------------------------- E1: hist
__global__ __launch_bounds__(256) void k_hist(const int* __restrict__ edst,
                                              int* __restrict__ cnt) {
    int e = blockIdx.x * 256 + threadIdx.x;
    if (e < NE) atomicAdd(&cnt[edst[e]], 1);
}

// ---------------------------------------------------------------- E2a/b/c: scan
__global__ void k_scanA(const int* __restrict__ cnt, int* __restrict__ bsum) {
    __shared__ int sm[1024];
    int tid = threadIdx.x;
    sm[tid] = cnt[blockIdx.x * 1024 + tid];
    __syncthreads();
    for (int s = 512; s > 0; s >>= 1) {
        if (tid < s) sm[tid] += sm[tid + s];
        __syncthreads();
    }
    if (tid == 0) bsum[blockIdx.x] = sm[0];
}

__global__ void k_scanB(int* __restrict__ bsum) {
    if (threadIdx.x == 0) {
        int run = 0;
        for (int b = 0; b < SCAN_B; ++b) { int t = bsum[b]; bsum[b] = run; run += t; }
    }
}

__global__ void k_scanC(const int* __restrict__ cnt, const int* __restrict__ bsum,
                        int* __restrict__ offs, int* __restrict__ curs) {
    __shared__ int sm[1024];
    int tid = threadIdx.x;
    int i = blockIdx.x * 1024 + tid;
    int v = cnt[i];
    sm[tid] = v;
    __syncthreads();
    for (int off = 1; off < 1024; off <<= 1) {       // Hillis-Steele inclusive
        int add = (tid >= off) ? sm[tid - off] : 0;
        __syncthreads();
        sm[tid] += add;
        __syncthreads();
    }
    int excl = sm[tid] - v + bsum[blockIdx.x];
    offs[i] = excl;
    if (i < NN) curs[i] = excl;
}

// ---------------------------------------------------------------- E3: scatter ids
__global__ __launch_bounds__(256) void k_scatter(const int* __restrict__ esrc,
                                                 const int* __restrict__ edst,
                                                 int* __restrict__ curs,
                                                 int2* __restrict__ pairs) {
    int e = blockIdx.x * 256 + threadIdx.x;
    if (e < NE) {
        int d = edst[e];
        int pos = atomicAdd(&curs[d], 1);
        pairs[pos] = make_int2(esrc[e], e);
    }
}

// ---------------------------------------------------------------- E4: gather
// One 64-lane wave per node; lane owns float2 of D. Inner loop 4-unrolled with
// clamped indices (loads unconditional -> batched) and masked accumulation.
__global__ __launch_bounds__(256) void k_gather(const float* __restrict__ nf,
                                                const float* __restrict__ ef,
                                                const int* __restrict__ offs,
                                                const int2* __restrict__ pairs,
                                                float* __restrict__ y) {
    int gt = blockIdx.x * 256 + threadIdx.x;
    int n = gt >> 6;                       // node = global wave id (grid exact)
    int lane = threadIdx.x & 63;
    const float2* ef2 = (const float2*)ef;
    const float2* nf2 = (const float2*)nf;
    int start = offs[n];
    int end   = offs[n + 1];
    float2 acc = nf2[(size_t)n * 64 + lane];          // residual baked in
    for (int base = start; base < end; base += 64) {
        int idx = base + lane;
        int2 pr = (idx < end) ? pairs[idx] : make_int2(0, 0);
        int cnt = min(64, end - base);
        for (int j0 = 0; j0 < cnt; j0 += 4) {
#pragma unroll
            for (int u = 0; u < 4; ++u) {             // 8 independent loads/group
                int j  = j0 + u;
                int jc = min(j, cnt - 1);             // clamp -> always valid
                int s = __shfl(pr.x, jc);
                int e = __shfl(pr.y, jc);
                float2 a = ef2[(size_t)e * 64 + lane];
                float2 b = nf2[(size_t)s * 64 + lane];
                float m0 = fmaxf(a.x + b.x, 0.0f);
                float m1 = fmaxf(a.y + b.y, 0.0f);
                if (j < cnt) { acc.x += m0; acc.y += m1; }   // mask, not branch-y loads
            }
        }
    }
    reinterpret_cast<float2*>(y)[(size_t)n * 64 + lane] = acc;
}

// ---------------------------------------------------------------- fallback path
__global__ __launch_bounds__(256) void k_init(const float* __restrict__ nf,
                                              float* __restrict__ acc,
                                              float* __restrict__ stats) {
    int i = blockIdx.x * 256 + threadIdx.x;
    reinterpret_cast<float4*>(acc)[i] = reinterpret_cast<const float4*>(nf)[i];
    if (blockIdx.x == 0) stats[threadIdx.x] = 0.0f;
}

__global__ __launch_bounds__(256) void k_edge(const float* __restrict__ nf,
                                              const float* __restrict__ ef,
                                              const int* __restrict__ esrc,
                                              const int* __restrict__ edst,
                                              float* __restrict__ acc) {
    const unsigned total = (unsigned)NE * 32u;
    const unsigned stride = gridDim.x * 256u;
    for (unsigned gid = blockIdx.x * 256u + threadIdx.x; gid < total; gid += stride) {
        unsigned e = gid >> 5;
        unsigned c = gid & 31u;
        int s = esrc[e];
        int d = edst[e];
        float4 hs = reinterpret_cast<const float4*>(nf + (size_t)s * DD)[c];
        float4 he = reinterpret_cast<const float4*>(ef + (size_t)e * DD)[c];
        float4 m;
        m.x = fmaxf(hs.x + he.x, 0.0f);
        m.y = fmaxf(hs.y + he.y, 0.0f);
        m.z = fmaxf(hs.z + he.z, 0.0f);
        m.w = fmaxf(hs.w + he.w, 0.0f);
        float* p = acc + (size_t)d * DD + c * 4u;
        unsafeAtomicAdd(p + 0, m.x);
        unsafeAtomicAdd(p + 1, m.y);
        unsafeAtomicAdd(p + 2, m.z);
        unsafeAtomicAdd(p + 3, m.w);
    }
}

// ---------------------------------------------------------------- K3: GEMM
__global__ __launch_bounds__(256, 1) void k_mlp(float* __restrict__ y,
                                                const float* __restrict__ Wm,
                                                const float* __restrict__ bias,
                                                float* __restrict__ stats) {
    __shared__ float Ws[DD][DD];        // (j,k) at col k ^ (((j>>4)&7)<<2)
    __shared__ float As[TN][DD];        // (n,k) at col k ^ (((n>>2)&7)<<2)
    __shared__ float ssum[DD];
    __shared__ float ssumsq[DD];

    const int tid = threadIdx.x;
    const int n0 = blockIdx.x * TN;

    for (int i = tid; i < DD * (DD / 4); i += 256) {
        int j  = i >> 5;
        int k4 = i & 31;
        float4 w = reinterpret_cast<const float4*>(Wm + j * DD)[k4];
        int ks = (k4 * 4) ^ (((j >> 4) & 7) << 2);
        *reinterpret_cast<float4*>(&Ws[j][ks]) = w;
    }
    for (int i = tid; i < TN * (DD / 4); i += 256) {
        int nl = i >> 5;
        int k4 = i & 31;
        int n  = n0 + nl;
        float4 a = make_float4(0.f, 0.f, 0.f, 0.f);
        if (n < NN) a = reinterpret_cast<const float4*>(y + (size_t)n * DD)[k4];
        int ks = (k4 * 4) ^ (((nl >> 2) & 7) << 2);
        *reinterpret_cast<float4*>(&As[nl][ks]) = a;
    }
    if (tid < DD) { ssum[tid] = 0.0f; ssumsq[tid] = 0.0f; }
    __syncthreads();

    const int ng = tid >> 3;
    const int jg = tid & 7;
    const int aswz = (ng & 7) << 2;
    const int wswz = jg << 2;
    const int nb = 4 * ng;

    float acc4[4][16];
#pragma unroll
    for (int i = 0; i < 4; ++i)
#pragma unroll
        for (int jj = 0; jj < 16; ++jj) acc4[i][jj] = 0.0f;

#pragma unroll 2
    for (int t = 0; t < DD / 4; ++t) {
        const int ka = (4 * t) ^ aswz;
        const int kw = (4 * t) ^ wswz;
        float4 a0 = *reinterpret_cast<const float4*>(&As[nb + 0][ka]);
        float4 a1 = *reinterpret_cast<const float4*>(&As[nb + 1][ka]);
        float4 a2 = *reinterpret_cast<const float4*>(&As[nb + 2][ka]);
        float4 a3 = *reinterpret_cast<const float4*>(&As[nb + 3][ka]);
#pragma unroll
        for (int jj = 0; jj < 16; ++jj) {
            float4 w = *reinterpret_cast<const float4*>(&Ws[16 * jg + jj][kw]);
            acc4[0][jj] = fmaf(a0.x, w.x, fmaf(a0.y, w.y, fmaf(a0.z, w.z, fmaf(a0.w, w.w, acc4[0][jj]))));
            acc4[1][jj] = fmaf(a1.x, w.x, fmaf(a1.y, w.y, fmaf(a1.z, w.z, fmaf(a1.w, w.w, acc4[1][jj]))));
            acc4[2][jj] = fmaf(a2.x, w.x, fmaf(a2.y, w.y, fmaf(a2.z, w.z, fmaf(a2.w, w.w, acc4[2][jj]))));
            acc4[3][jj] = fmaf(a3.x, w.x, fmaf(a3.y, w.y, fmaf(a3.z, w.z, fmaf(a3.w, w.w, acc4[3][jj]))));
        }
    }

    float psum[16], psq[16];
#pragma unroll
    for (int jj = 0; jj < 16; ++jj) { psum[jj] = 0.0f; psq[jj] = 0.0f; }

#pragma unroll
    for (int i = 0; i < 4; ++i) {
        int n = n0 + nb + i;
        if (n < NN) {
            float out[16];
#pragma unroll
            for (int jj = 0; jj < 16; ++jj) {
                float v = acc4[i][jj] + bias[16 * jg + jj];
                v = (v >= 0.0f) ? v : 0.01f * v;
                out[jj] = v;
                psum[jj] += v;
                psq[jj]  += v * v;
            }
            float4* dst = reinterpret_cast<float4*>(y + (size_t)n * DD + 16 * jg);
            dst[0] = make_float4(out[0],  out[1],  out[2],  out[3]);
            dst[1] = make_float4(out[4],  out[5],  out[6],  out[7]);
            dst[2] = make_float4(out[8],  out[9],  out[10], out[11]);
            dst[3] = make_float4(out[12], out[13], out[14], out[15]);
        }
    }
#pragma unroll
    for (int jj = 0; jj < 16; ++jj) {
        atomicAdd(&ssum[16 * jg + jj], psum[jj]);
        atomicAdd(&ssumsq[16 * jg + jj], psq[jj]);
    }
    __syncthreads();
    if (tid < DD) {
        unsafeAtomicAdd(&stats[tid],      ssum[tid]);
        unsafeAtomicAdd(&stats[DD + tid], ssumsq[tid]);
    }
}

// ---------------------------------------------------------------- K4: stats
__global__ void k_stats(float* __restrict__ stats,
                        const float* __restrict__ gamma,
                        const float* __restrict__ beta) {
    int j = threadIdx.x;
    if (j < DD) {
        float inv_n = 1.0f / (float)NN;
        float mean = stats[j] * inv_n;
        float var  = stats[DD + j] * inv_n - mean * mean;
        float s = gamma[j] * rsqrtf(var + 1e-5f);
        stats[2 * DD + j] = s;
        stats[3 * DD + j] = beta[j] - mean * s;
    }
}

// ---------------------------------------------------------------- K5: BN
__global__ __launch_bounds__(256) void k_bn(float* __restrict__ y,
                                            const float* __restrict__ stats) {
    int i = blockIdx.x * 256 + threadIdx.x;
    int k4 = i & 31;
    float4 sc = reinterpret_cast<const float4*>(stats + 2 * DD)[k4];
    float4 sh = reinterpret_cast<const float4*>(stats + 3 * DD)[k4];
    float4 v = reinterpret_cast<float4*>(y)[i];
    v.x = fmaf(v.x, sc.x, sh.x);
    v.y = fmaf(v.y, sc.y, sh.y);
    v.z = fmaf(v.z, sc.z, sh.z);
    v.w = fmaf(v.w, sc.w, sh.w);
    reinterpret_cast<float4*>(y)[i] = v;
}

extern "C" void kernel_launch(void* const* d_in, const int* in_sizes, int n_in,
                              void* d_out, int out_size, void* d_ws, size_t ws_size,
                              hipStream_t stream) {
    const float* nf    = (const float*)d_in[0];
    const float* ef    = (const float*)d_in[1];
    const int*   esrc  = (const int*)d_in[2];
    const int*   edst  = (const int*)d_in[3];
    const float* Wm    = (const float*)d_in[4];
    const float* bias  = (const float*)d_in[5];
    const float* gamma = (const float*)d_in[6];
    const float* beta  = (const float*)d_in[7];
    float* y = (float*)d_out;
    char* ws = (char*)d_ws;

    float* stats = (float*)(ws + WS_STATS);
    int*   bsum  = (int*)(ws + WS_BSUM);
    int*   cnt   = (int*)(ws + WS_CNT);
    int*   offs  = (int*)(ws + WS_OFFS);
    int*   curs  = (int*)(ws + WS_CURS);
    int2*  pairs = (int2*)(ws + WS_PAIRS);

    const int vec_blocks = (NN * DD / 4) / 256;             // 5000, exact
    const int edge_blocks = (NE + 255) / 256;               // 2500

    if (ws_size >= WS_NEEDED) {
        k_zero<<<(SCAN_B * 1024 + 512 + 255) / 256, 256, 0, stream>>>(cnt, stats);
        k_hist<<<edge_blocks, 256, 0, stream>>>(edst, cnt);
        k_scanA<<<SCAN_B, 1024, 0, stream>>>(cnt, bsum);
        k_scanB<<<1, 64, 0, stream>>>(bsum);
        k_scanC<<<SCAN_B, 1024, 0, stream>>>(cnt, bsum, offs, curs);
        k_scatter<<<edge_blocks, 256, 0, stream>>>(esrc, edst, curs, pairs);
        k_gather<<<NN * 64 / 256, 256, 0, stream>>>(nf, ef, offs, pairs, y);
    } else {
        // fallback: atomic scatter path (proven correct, slower)
        k_init<<<vec_blocks, 256, 0, stream>>>(nf, y, stats);
        k_edge<<<2048, 256, 0, stream>>>(nf, ef, esrc, edst, y);
    }
    k_mlp<<<(NN + TN - 1) / TN, 256, 0, stream>>>(y, Wm, bias, stats);
    k_stats<<<1, 128, 0, stream>>>(stats, gamma, beta);
    k_bn<<<vec_blocks, 256, 0, stream>>>(y, stats);
}